// Round 15
// baseline (129.477 us; speedup 1.0000x reference)
//
#include <hip/hip_runtime.h>
#include <hip/hip_bf16.h>
#include <stdint.h>

typedef __attribute__((ext_vector_type(8))) short bf16x8;
typedef __attribute__((ext_vector_type(4))) float f32x4;

#define NB 8192

__device__ __forceinline__ unsigned pkbf(float x, float y) {
    __hip_bfloat162 h = __float22bfloat162_rn(make_float2(x, y));  // v_cvt_pk_bf16_f32 (RNE)
    unsigned r;
    __builtin_memcpy(&r, &h, 4);
    return r;
}

__device__ __forceinline__ uint4 pack8(float4 a, float4 b) {
    uint4 r;
    r.x = pkbf(a.x, a.y);
    r.y = pkbf(a.z, a.w);
    r.z = pkbf(b.x, b.y);
    r.w = pkbf(b.z, b.w);
    return r;
}

__device__ __forceinline__ void gload16(const float* g, void* l) {
    __builtin_amdgcn_global_load_lds(
        (const __attribute__((address_space(1))) void*)g,
        (__attribute__((address_space(3))) void*)l, 16, 0, 0);
}

// ---------------------------------------------------------------------------
// prep_w: W[512][2048] fp32 -> bf16 fragment-linear (B operand). Unchanged.
// Fragment (kb,cb): uint4 index (kb*32+cb)*64 + lane;
// elem j = W[cb*16 + (lane&15)][kb*32 + (lane>>4)*8 + j]
// ---------------------------------------------------------------------------
__global__ __launch_bounds__(256)
void prep_w_kernel(const float* __restrict__ W, uint4* __restrict__ Wt) {
    int t = blockIdx.x * 256 + threadIdx.x;
    int lane = t & 63;
    int frag = t >> 6;
    int kb = frag >> 5, cb = frag & 31;
    int o = cb * 16 + (lane & 15);
    int k = kb * 32 + ((lane >> 4) << 3);
    const float* src = W + (size_t)o * 2048 + k;
    Wt[t] = pack8(*(const float4*)src, *(const float4*)(src + 4));
}

// ---------------------------------------------------------------------------
// score v17: 768 blocks x 512 thr (8 waves), node=bid%6, tile=bid/6, BM=64,
// BN=512 (wave w: cols [w*64,+64)), acc[4][4]=64 AGPR.
//
// FIFO-CLEAN PIPELINE (the r1-r14 failure): vmcnt is FIFO, so any B load
// issued AFTER an in-flight DMA forces the DMA to drain at the first
// B-wait. v17 per buffer s:
//   1. preload ALL B(s) into regs (16 L2 loads)      <- OLDEST in queue
//   2. issue 4x global_load_lds for buffer s+1        <- NEWEST
//   3. compute 4 kbh (B-waits are counted waits on the pre-DMA loads ->
//      the DMA streams untouched across the whole compute phase)
//   4. __syncthreads (drains the DMA that has been in flight all along)
// Per-CU duty: DMA 32KB @ ~10B/cyc = 3200cyc >> compute ~1600cyc -> the
// kernel becomes A-stream-bound by construction (floor ~134MB / 6TB/s).
//
// LDS: 2 x 32KB fp32 buffers [64 rows][128 k] (512B row = 32 16B slots).
// Swizzle (full-row window, fixes r13/r14's 8-slot fold):
//   phys = s ^ ((u<<1)&31) ^ (u>>3), u = row&15
// applied on the per-lane GLOBAL source (DMA dest stays linear, wave-
// uniform base) and on ds_read -> max 4-way conflict (1.58x, tolerable).
// fp32->bf16 cvt on read (v_cvt_pk RNE, same numerics as all rounds).
// ---------------------------------------------------------------------------
template<int DN>
__device__ __forceinline__ void score_body(
        const float* __restrict__ xp, int node, int tile,
        const float* __restrict__ bias, const float* __restrict__ hvec,
        const uint4* __restrict__ Wt, float* __restrict__ scores,
        char* lds, float* red) {
    constexpr int NBUF = DN / 128;     // 8 heavy, 4 light
    int t = threadIdx.x;
    int l = t & 63;
    int w = t >> 6;
    int m0 = tile << 6;
    int j0 = w << 2;                   // this wave's DMA-instr / B-col base

    // DMA write-side geometry: instr i covers rows 2*(j0+i), 2*(j0+i)+1.
    // lane l -> row r = 2*(j0+i) + (l>>5), phys slot p = l&31;
    // global logical slot = p ^ SW(r&15), SW(u) = ((u<<1)&31) ^ (u>>3).
    int rI[4], gq[4];
#pragma unroll
    for (int i = 0; i < 4; ++i) {
        int r = ((j0 + i) << 1) + (l >> 5);
        int u = r & 15;
        int sL = (l & 31) ^ (((u << 1) & 31) ^ (u >> 3));
        rI[i] = r;
        gq[i] = sL << 2;               // fp32 offset within 128-k slab
    }

    f32x4 acc[4][4];
#pragma unroll
    for (int mf = 0; mf < 4; ++mf)
#pragma unroll
        for (int nf = 0; nf < 4; ++nf)
            acc[mf][nf] = (f32x4){0.f, 0.f, 0.f, 0.f};

    // prologue: DMA buffer 0
#pragma unroll
    for (int i = 0; i < 4; ++i)
        gload16(xp + (size_t)(m0 + rI[i]) * DN + gq[i],
                lds + ((j0 + i) << 10));
    __syncthreads();

    int p = 0;
    // read-side swizzle constant (independent of mf/kbh): u = l&15
    int swz = (((l & 15) << 1) & 31) ^ ((l & 15) >> 3);

    for (int s = 0; s < NBUF; ++s) {
        // 1. preload ALL B for this buffer (oldest in vmem queue)
        uint4 breg[4][4];
#pragma unroll
        for (int kbh = 0; kbh < 4; ++kbh) {
            int kb = (s << 2) + kbh;
#pragma unroll
            for (int nf = 0; nf < 4; ++nf)
                breg[kbh][nf] = Wt[(((kb << 5) + j0 + nf) << 6) + l];
        }
        __builtin_amdgcn_sched_barrier(0);
        // 2. DMA buffer s+1 (newest; streams across the compute below)
        if (s + 1 < NBUF) {
            int koff = (s + 1) << 7;
#pragma unroll
            for (int i = 0; i < 4; ++i)
                gload16(xp + (size_t)(m0 + rI[i]) * DN + koff + gq[i],
                        lds + ((p ^ 1) << 15) + ((j0 + i) << 10));
        }
        __builtin_amdgcn_sched_barrier(0);
        // 3. compute 4 kbh from buffer p (B-waits counted: don't touch DMA)
        const char* buf = lds + (p << 15);
#pragma unroll
        for (int kbh = 0; kbh < 4; ++kbh) {
#pragma unroll
            for (int mf = 0; mf < 4; ++mf) {
                int r = (mf << 4) + (l & 15);
                int ph0 = ((kbh << 3) + ((l >> 4) << 1)) ^ swz;
                const char* rp = buf + r * 512;
                float4 lo = *(const float4*)(rp + (ph0 << 4));
                float4 hi = *(const float4*)(rp + ((ph0 ^ 1) << 4));
                uint4 pk = pack8(lo, hi);
                bf16x8 afr;
                __builtin_memcpy(&afr, &pk, 16);
#pragma unroll
                for (int nf = 0; nf < 4; ++nf) {
                    bf16x8 bfr;
                    __builtin_memcpy(&bfr, &breg[kbh][nf], 16);
                    acc[mf][nf] = __builtin_amdgcn_mfma_f32_16x16x32_bf16(
                        afr, bfr, acc[mf][nf], 0, 0, 0);
                }
            }
        }
        // 4. drain DMA (landed during compute) + LDS read-safety
        __syncthreads();
        p ^= 1;
    }

    // epilogue: tanh, dot with h, reduce to per-row score
    float bv[4], hv[4];
#pragma unroll
    for (int nf = 0; nf < 4; ++nf) {
        int o = (w << 6) + (nf << 4) + (l & 15);
        bv[nf] = bias[o];
        hv[nf] = hvec[o];
    }
#pragma unroll
    for (int mf = 0; mf < 4; ++mf) {
        float sc[4] = {0.f, 0.f, 0.f, 0.f};
#pragma unroll
        for (int nf = 0; nf < 4; ++nf) {
#pragma unroll
            for (int r = 0; r < 4; ++r) {
                float xv = acc[mf][nf][r] + bv[nf];
                float th = 1.f - 2.f * __builtin_amdgcn_rcpf(1.f + __expf(2.f * xv));
                sc[r] = fmaf(hv[nf], th, sc[r]);
            }
        }
#pragma unroll
        for (int r = 0; r < 4; ++r) {
            float v = sc[r];
            v += __shfl_xor(v, 1);
            v += __shfl_xor(v, 2);
            v += __shfl_xor(v, 4);
            v += __shfl_xor(v, 8);
            if ((l & 15) == 0)
                red[(w << 6) + (mf << 4) + ((l >> 4) << 2) + r] = v;
        }
    }
    __syncthreads();
    if (t < 64) {
        float ssum = 0.f;
#pragma unroll
        for (int w2 = 0; w2 < 8; ++w2) ssum += red[(w2 << 6) + t];
        scores[node * NB + m0 + t] = ssum;
    }
}

__global__ __launch_bounds__(512)
void score_kernel(const float* __restrict__ x0, const float* __restrict__ x1,
                  const float* __restrict__ x2, const float* __restrict__ x3,
                  const float* __restrict__ x4, const float* __restrict__ x5,
                  const float* __restrict__ bias, const float* __restrict__ hvec,
                  const uint4* __restrict__ Wt, float* __restrict__ scores) {
    __shared__ char lds[65536];       // 2 x 32KB fp32 A buffers
    __shared__ float red[8 * 64];     // 2 KB
    int bid = blockIdx.x;
    int node = bid % 6;
    int tile = bid / 6;
    switch (node) {
        case 0: score_body<1024>(x0, 0, tile, bias, hvec, Wt, scores, lds, red); break;
        case 1: score_body<512>(x1, 1, tile, bias, hvec, Wt, scores, lds, red); break;
        case 2: score_body<512>(x2, 2, tile, bias, hvec, Wt, scores, lds, red); break;
        case 3: score_body<512>(x3, 3, tile, bias, hvec, Wt, scores, lds, red); break;
        case 4: score_body<1024>(x4, 4, tile, bias, hvec, Wt, scores, lds, red); break;
        default: score_body<512>(x5, 5, tile, bias, hvec, Wt, scores, lds, red); break;
    }
}

// ---------------------------------------------------------------------------
// z kernel: one wave per batch. softmax over 6 scores, then
// z[0:512]=sum beta_n x_n ; z[512:1024]=b0*ls+b4*ds ; z[1024:2048]=0
// ---------------------------------------------------------------------------
__global__ __launch_bounds__(256)
void z_kernel(const float* __restrict__ x0, const float* __restrict__ x1,
              const float* __restrict__ x2, const float* __restrict__ x3,
              const float* __restrict__ x4, const float* __restrict__ x5,
              const float* __restrict__ scores, float* __restrict__ out) {
    int wv = threadIdx.x >> 6;
    int lane = threadIdx.x & 63;
    int b = (blockIdx.x << 2) + wv;

    float s0 = scores[b];
    float s1 = scores[NB + b];
    float s2 = scores[2 * NB + b];
    float s3 = scores[3 * NB + b];
    float s4 = scores[4 * NB + b];
    float s5 = scores[5 * NB + b];
    float m = fmaxf(fmaxf(fmaxf(s0, s1), fmaxf(s2, s3)), fmaxf(s4, s5));
    float e0 = __expf(s0 - m), e1 = __expf(s1 - m), e2 = __expf(s2 - m);
    float e3 = __expf(s3 - m), e4 = __expf(s4 - m), e5 = __expf(s5 - m);
    float inv = __builtin_amdgcn_rcpf(e0 + e1 + e2 + e3 + e4 + e5);
    float b0 = e0 * inv, b1 = e1 * inv, b2 = e2 * inv;
    float b3 = e3 * inv, b4 = e4 * inv, b5 = e5 * inv;

    const float* pls = x0 + (size_t)b * 1024;
    const float* pA  = x1 + (size_t)b * 512;
    const float* plm = x2 + (size_t)b * 512;
    const float* pAT = x3 + (size_t)b * 512;
    const float* pds = x4 + (size_t)b * 1024;
    const float* pdm = x5 + (size_t)b * 512;
    float* po = out + (size_t)b * 2048;

#pragma unroll
    for (int j = 0; j < 2; ++j) {
        int c = (j << 8) + (lane << 2);
        float4 vls = *(const float4*)(pls + c);
        float4 vA  = *(const float4*)(pA + c);
        float4 vlm = *(const float4*)(plm + c);
        float4 vAT = *(const float4*)(pAT + c);
        float4 vds = *(const float4*)(pds + c);
        float4 vdm = *(const float4*)(pdm + c);
        float4 r;
        r.x = b0*vls.x + b1*vA.x + b2*vlm.x + b3*vAT.x + b4*vds.x + b5*vdm.x;
        r.y = b0*vls.y + b1*vA.y + b2*vlm.y + b3*vAT.y + b4*vds.y + b5*vdm.y;
        r.z = b0*vls.z + b1*vA.z + b2*vlm.z + b3*vAT.z + b4*vds.z + b5*vdm.z;
        r.w = b0*vls.w + b1*vA.w + b2*vlm.w + b3*vAT.w + b4*vds.w + b5*vdm.w;
        *(float4*)(po + c) = r;
    }
#pragma unroll
    for (int j = 0; j < 2; ++j) {
        int c = 512 + (j << 8) + (lane << 2);
        float4 vls = *(const float4*)(pls + c);
        float4 vds = *(const float4*)(pds + c);
        float4 r;
        r.x = b0*vls.x + b4*vds.x;
        r.y = b0*vls.y + b4*vds.y;
        r.z = b0*vls.z + b4*vds.z;
        r.w = b0*vls.w + b4*vds.w;
        *(float4*)(po + c) = r;
    }
    float4 zz = make_float4(0.f, 0.f, 0.f, 0.f);
#pragma unroll
    for (int j = 0; j < 4; ++j) {
        int c = 1024 + (j << 8) + (lane << 2);
        *(float4*)(po + c) = zz;
    }
}

extern "C" void kernel_launch(void* const* d_in, const int* in_sizes, int n_in,
                              void* d_out, int out_size, void* d_ws, size_t ws_size,
                              hipStream_t stream) {
    const float* x0   = (const float*)d_in[0];  // ls  [8192,1024]
    const float* x1   = (const float*)d_in[1];  // A   [8192,512]
    const float* x2   = (const float*)d_in[2];  // lm  [8192,512]
    const float* x3   = (const float*)d_in[3];  // AT  [8192,512]
    const float* x4   = (const float*)d_in[4];  // ds  [8192,1024]
    const float* x5   = (const float*)d_in[5];  // dm  [8192,512]
    const float* W    = (const float*)d_in[6];  // [512,2048]
    const float* bias = (const float*)d_in[7];  // [512]
    const float* hvec = (const float*)d_in[8];  // [512,1]

    uint4* Wt = (uint4*)d_ws;                              // 1 MB
    float* scores = (float*)((char*)d_ws + (1u << 20));    // 192 KB

    prep_w_kernel<<<256, 256, 0, stream>>>(W, Wt);
    score_kernel<<<768, 512, 0, stream>>>(x0, x1, x2, x3, x4, x5, bias, hvec, Wt, scores);
    z_kernel<<<2048, 256, 0, stream>>>(x0, x1, x2, x3, x4, x5, scores, (float*)d_out);
}